// Round 13
// baseline (558.521 us; speedup 1.0000x reference)
//
#include <hip/hip_runtime.h>
#include <hip/hip_bf16.h>

// Round 13: 64 rows/block — amortize B-fragment loads over 4 row-groups.
// R9-R12 all plateaued ~180 µs: P1's L2 traffic (each 16-row block re-read
// the whole 512 KB B) + store stream stacked.  Now each compute wave holds
// 4 A-pairs and does 8 MFMA per 2 B-loads: L2 traffic 1.07 GB -> 268 MB,
// per-chunk overhead /4.  Grid 512 = exactly 2 blocks/CU, one cohort.
// Producer/consumer waves kept (R12): waves 0-3 compute (loads only in
// their vmcnt stream), waves 4-7 stream the block's 1 MB zero weights +
// out_read zeros; B1's implicit vmcnt(0) drains zeros before any dirty
// overwrite.  Gate: weight survives shrink iff logit t > tau =
// ln(lambda*S) - 1e-3 (per-lane: max over its 16 rows vs min-tau over the
// same 16 rows; ballot covers all rows x cols).  Dirty path (rare, e.g.
// adversarial inputs) recomputes only dirty groups bit-identically and
// atomicAdds read partials.

#define NM 4096
#define HD 64
#define NROWS 32768   // 16*2048
#define RPB 64        // rows per block
#define NBLK (NROWS / RPB)  // 512

typedef short bf16x8 __attribute__((ext_vector_type(8)));
typedef float f32x4  __attribute__((ext_vector_type(4)));

// ---- prep: normalized x rows -> bf16 [row][k], scale folded in ----
__global__ __launch_bounds__(256) void prep_rows(const float* __restrict__ src,
                                                 ushort* __restrict__ dst,
                                                 float scale) {
    const int wave = threadIdx.x >> 6, lane = threadIdx.x & 63;
    const long row = (long)blockIdx.x * 4 + wave;
    float v = src[row * HD + lane];
    float s = v * v;
#pragma unroll
    for (int o = 32; o; o >>= 1) s += __shfl_xor(s, o, 64);
    const float inv = scale / fmaxf(sqrtf(s), 1e-12f);
    __hip_bfloat16 h = __float2bfloat16(v * inv);
    dst[row * HD + lane] = *reinterpret_cast<ushort*>(&h);
}

// ---- prep: normalized memories -> swizzled MFMA B-fragment order ----
__global__ __launch_bounds__(256) void prep_m_swz(const float* __restrict__ mem,
                                                  ushort* __restrict__ mbs) {
    const int wave = threadIdx.x >> 6, lane = threadIdx.x & 63;
    const int row = blockIdx.x * 4 + wave;   // n
    float v = mem[row * HD + lane];          // k = lane
    float s = v * v;
#pragma unroll
    for (int o = 32; o; o >>= 1) s += __shfl_xor(s, o, 64);
    const float inv = 1.0f / fmaxf(sqrtf(s), 1e-12f);
    __hip_bfloat16 h = __float2bfloat16(v * inv);
    const int t = row >> 4, c = row & 15;
    const int k = lane;
    const int f = k >> 5, q = (k >> 3) & 3, j = k & 7;
    mbs[(long)t * 1024 + f * 512 + (q * 16 + c) * 8 + j] =
        *reinterpret_cast<ushort*>(&h);
}

// A-frag: lane holds xb[row0+(lane&15)][q*8..+7], q=lane>>4.
// C/D: col = lane&15, row = q*4 + reg   [verified layout, learn_hip m89/m91].
__global__ __launch_bounds__(512, 4) void k_ps64(const ushort* __restrict__ xb,
                                                 const ushort* __restrict__ mbs,
                                                 const float* __restrict__ mem,
                                                 float* __restrict__ out_w,
                                                 float* __restrict__ out_read) {
    const int tid = threadIdx.x;
    const int wv = tid >> 6, lane = tid & 63;   // wv 0..7
    const int m0 = blockIdx.x * RPB;

    __shared__ float sS[4][RPB];
    __shared__ float sL[4][RPB];
    __shared__ uint  sD[4];

    const float4 z4 = make_float4(0.0f, 0.0f, 0.0f, 0.0f);

    if (wv >= 4) {
        // ================= storer waves (4..7) =================
        const int sw = wv - 4;
        float4* base = (float4*)(out_w + (long)m0 * NM);   // 65536 float4
#pragma unroll 8
        for (int it = 0; it < 256; it++)
            base[it * 256 + sw * 64 + lane] = z4;          // 1 KB/instr
        float4* rb = (float4*)(out_read + (long)m0 * HD);  // 1024 float4
#pragma unroll
        for (int it = 0; it < 4; it++)
            rb[(sw * 4 + it) * 64 + lane] = z4;
        __syncthreads();   // B1: implicit vmcnt(0) drains this wave's zeros
        __syncthreads();   // B2
        if (sD[0] | sD[1] | sD[2] | sD[3]) __syncthreads();  // B3 (rare)
        return;
    }

    // ================= compute waves (0..3) =================
    const int q = lane >> 4, c = lane & 15;
    bf16x8 a0[4], a1[4];
#pragma unroll
    for (int rg = 0; rg < 4; rg++) {
        const ushort* ap = xb + (long)(m0 + rg * 16 + c) * HD + q * 8;
        a0[rg] = *(const bf16x8*)(ap);
        a1[rg] = *(const bf16x8*)(ap + 32);
    }
    const ushort* mstrip = mbs + (long)(wv * 64) * 1024;   // wave's 64 chunks

    // ---- P1: sum-exp for 16 owned rows + coarse gate bank ----
    float sm[16];
#pragma unroll
    for (int k = 0; k < 16; k++) sm[k] = 0.0f;
    float tmax8[8];
    for (int g = 0; g < 8; g++) {
        float tm = -1e30f;
#pragma unroll 2
        for (int ii = 0; ii < 8; ii++) {
            const int i = g * 8 + ii;
            const ushort* mc = mstrip + (long)i * 1024 + lane * 8;
            const bf16x8 b0 = *(const bf16x8*)(mc);
            const bf16x8 b1 = *(const bf16x8*)(mc + 512);
#pragma unroll
            for (int rg = 0; rg < 4; rg++) {
                f32x4 t = {0.0f, 0.0f, 0.0f, 0.0f};
                t = __builtin_amdgcn_mfma_f32_16x16x32_bf16(a0[rg], b0, t, 0, 0, 0);
                t = __builtin_amdgcn_mfma_f32_16x16x32_bf16(a1[rg], b1, t, 0, 0, 0);
                tm = fmaxf(tm, fmaxf(fmaxf(t[0], t[1]), fmaxf(t[2], t[3])));
#pragma unroll
                for (int r = 0; r < 4; r++) sm[rg * 4 + r] += __expf(t[r]);
            }
        }
        tmax8[g] = tm;
    }
#pragma unroll
    for (int o = 1; o < 16; o <<= 1)
#pragma unroll
        for (int k = 0; k < 16; k++) sm[k] += __shfl_xor(sm[k], o, 64);
    if (c == 0)
#pragma unroll
        for (int k = 0; k < 16; k++)
            sS[wv][(k >> 2) * 16 + q * 4 + (k & 3)] = sm[k];
    __syncthreads();   // B1 (joins storer drain)
    float rS[16], tmin = 1e30f;
#pragma unroll
    for (int k = 0; k < 16; k++) {
        const int row = (k >> 2) * 16 + q * 4 + (k & 3);
        const float S = sS[0][row] + sS[1][row] + sS[2][row] + sS[3][row];
        rS[k] = 1.0f / S;
        tmin = fminf(tmin, __logf(0.0025f * S) - 1e-3f);  // conservative tau
    }
    uint dmask = 0;
#pragma unroll
    for (int g = 0; g < 8; g++)
        if (__ballot(tmax8[g] > tmin)) dmask |= 1u << g;
    if (lane == 0) sD[wv] = dmask;
    __syncthreads();   // B2
    if (!(sD[0] | sD[1] | sD[2] | sD[3]))
        return;  // clean (common): storers already wrote everything

    // ================= dirty block (rare): exact path =================
    // gated L1 (recompute only dirty groups; clean groups contribute 0)
    float l1[16];
#pragma unroll
    for (int k = 0; k < 16; k++) l1[k] = 0.0f;
    for (int g = 0; g < 8; g++) {
        if (!((dmask >> g) & 1u)) continue;   // wave-uniform
        for (int ii = 0; ii < 8; ii++) {
            const int i = g * 8 + ii;
            const ushort* mc = mstrip + (long)i * 1024 + lane * 8;
            const bf16x8 b0 = *(const bf16x8*)(mc);
            const bf16x8 b1 = *(const bf16x8*)(mc + 512);
#pragma unroll
            for (int rg = 0; rg < 4; rg++) {
                f32x4 t = {0.0f, 0.0f, 0.0f, 0.0f};
                t = __builtin_amdgcn_mfma_f32_16x16x32_bf16(a0[rg], b0, t, 0, 0, 0);
                t = __builtin_amdgcn_mfma_f32_16x16x32_bf16(a1[rg], b1, t, 0, 0, 0);
#pragma unroll
                for (int r = 0; r < 4; r++) {
                    float w = __expf(t[r]) * rS[rg * 4 + r];
                    float d = w - 0.0025f;
                    l1[rg * 4 + r] +=
                        __fdividef(fmaxf(d, 0.0f) * w, fabsf(d) + 1e-12f);
                }
            }
        }
    }
#pragma unroll
    for (int o = 1; o < 16; o <<= 1)
#pragma unroll
        for (int k = 0; k < 16; k++) l1[k] += __shfl_xor(l1[k], o, 64);
    if (c == 0)
#pragma unroll
        for (int k = 0; k < 16; k++)
            sL[wv][(k >> 2) * 16 + q * 4 + (k & 3)] = l1[k];
    __syncthreads();   // B3
    float rL[16];
#pragma unroll
    for (int k = 0; k < 16; k++) {
        const int row = (k >> 2) * 16 + q * 4 + (k & 3);
        rL[k] = 1.0f / fmaxf(sL[0][row] + sL[1][row] + sL[2][row] + sL[3][row],
                             1e-12f);
    }

    // recompute ONLY dirty groups: exact weights overwrite drained zeros;
    // ballot-sparse read accumulation -> atomicAdd (out_read pre-zeroed).
    for (int rg = 0; rg < 4; rg++) {
        float racc[16];
#pragma unroll
        for (int k = 0; k < 16; k++) racc[k] = 0.0f;
        bool anyr = false;
        float* wbase = out_w + (long)(m0 + rg * 16 + q * 4) * NM + c;
        for (int g = 0; g < 8; g++) {
            if (!((dmask >> g) & 1u)) continue;
            for (int ii = 0; ii < 8; ii++) {
                const int i = g * 8 + ii;
                const int n0 = wv * 1024 + i * 16;
                const ushort* mc = mstrip + (long)i * 1024 + lane * 8;
                const bf16x8 b0 = *(const bf16x8*)(mc);
                const bf16x8 b1 = *(const bf16x8*)(mc + 512);
                f32x4 t = {0.0f, 0.0f, 0.0f, 0.0f};
                t = __builtin_amdgcn_mfma_f32_16x16x32_bf16(a0[rg], b0, t, 0, 0, 0);
                t = __builtin_amdgcn_mfma_f32_16x16x32_bf16(a1[rg], b1, t, 0, 0, 0);
                float wf[4];
#pragma unroll
                for (int r = 0; r < 4; r++) {
                    float w  = __expf(t[r]) * rS[rg * 4 + r];
                    float d  = w - 0.0025f;
                    float sh = __fdividef(fmaxf(d, 0.0f) * w, fabsf(d) + 1e-12f);
                    wf[r] = sh * rL[rg * 4 + r];
                    wbase[(long)r * NM + n0] = wf[r];
                }
                const bool nz = (wf[0] != 0.0f) | (wf[1] != 0.0f) |
                                (wf[2] != 0.0f) | (wf[3] != 0.0f);
                unsigned long long mask = __ballot(nz);
                if (mask) anyr = true;
                while (mask) {
                    const int j = __ffsll((long long)mask) - 1;
                    mask &= (mask - 1);
                    const int qj = j >> 4, cj = j & 15;
                    float b0v = __shfl(wf[0], j, 64), b1v = __shfl(wf[1], j, 64);
                    float b2v = __shfl(wf[2], j, 64), b3v = __shfl(wf[3], j, 64);
                    const float mv = mem[(long)(n0 + cj) * HD + lane];
                    switch (qj) {  // wave-uniform branch
                        case 0: racc[0]  += b0v * mv; racc[1]  += b1v * mv;
                                racc[2]  += b2v * mv; racc[3]  += b3v * mv; break;
                        case 1: racc[4]  += b0v * mv; racc[5]  += b1v * mv;
                                racc[6]  += b2v * mv; racc[7]  += b3v * mv; break;
                        case 2: racc[8]  += b0v * mv; racc[9]  += b1v * mv;
                                racc[10] += b2v * mv; racc[11] += b3v * mv; break;
                        default: racc[12] += b0v * mv; racc[13] += b1v * mv;
                                 racc[14] += b2v * mv; racc[15] += b3v * mv; break;
                    }
                }
            }
        }
        if (anyr) {
#pragma unroll
            for (int k = 0; k < 16; k++)
                atomicAdd(out_read + (long)(m0 + rg * 16 + k) * HD + lane,
                          racc[k]);
        }
    }
}

extern "C" void kernel_launch(void* const* d_in, const int* in_sizes, int n_in,
                              void* d_out, int out_size, void* d_ws, size_t ws_size,
                              hipStream_t stream) {
    const float* x   = (const float*)d_in[0];
    const float* mem = (const float*)d_in[1];
    ushort* xb       = (ushort*)d_ws;                 // 4 MB
    ushort* mbs      = xb + (long)NROWS * HD;         // 512 KB (swizzled B)
    float* out_read  = (float*)d_out;                 // [32768*64]
    float* out_w     = out_read + (long)NROWS * HD;   // [32768*4096]

    prep_rows<<<NROWS / 4, 256, 0, stream>>>(x, xb, 2.0f);  // 1/T folded
    prep_m_swz<<<NM / 4, 256, 0, stream>>>(mem, mbs);
    k_ps64<<<NBLK, 512, 0, stream>>>(xb, mbs, mem, out_w, out_read);
}

// Round 14
// 549.708 us; speedup vs baseline: 1.0160x; 1.0160x over previous
//
#include <hip/hip_runtime.h>
#include <hip/hip_bf16.h>

// Round 14: occupancy-first hot/cold split.
// Evidence: R2 finish (same 134M exps + 1.08 GB stream) ran 200 µs at
// 5.4 TB/s with 32 waves/CU and ~0 LDS; every R8+ variant runs <=16
// waves/CU (big LDS, 512-thr blocks, dirty-path VGPR) and plateaus ~180.
// Fix: hot kernel carries NOTHING but P1 + zero-stores.
//   k_main (hot, 32 waves/CU target): 256 thr, 16 rows/block, LDS 320 B,
//     launch_bounds(256,8).  P1 sum-exp via MFMA with one interleaved
//     1 KB zero-store per chunk (vmcnt store/load coupling hidden by 8
//     waves/SIMD); then S, tau=ln(lambda*S)-1e-3, ballot gate ->
//     masks[] + per-row S -> ws; zero out_read; exit.  No dirty code.
//   k_fix (cold): clean block (common: max w ~6e-4 << lambda) returns
//     after 1 load + LDS-OR.  Dirty: recompute bit-identically (same
//     MFMA/exp bits, rS from stored S), gated L1, exact weights overwrite
//     the (kernel-boundary-drained) zeros, ballot-sparse read ->
//     atomicAdd into pre-zeroed out_read.

#define NM 4096
#define HD 64
#define NROWS 32768  // 16*2048

typedef short bf16x8 __attribute__((ext_vector_type(8)));
typedef float f32x4  __attribute__((ext_vector_type(4)));

// ---- prep: normalized x rows -> bf16 [row][k], scale folded in ----
__global__ __launch_bounds__(256) void prep_rows(const float* __restrict__ src,
                                                 ushort* __restrict__ dst,
                                                 float scale) {
    const int wave = threadIdx.x >> 6, lane = threadIdx.x & 63;
    const long row = (long)blockIdx.x * 4 + wave;
    float v = src[row * HD + lane];
    float s = v * v;
#pragma unroll
    for (int o = 32; o; o >>= 1) s += __shfl_xor(s, o, 64);
    const float inv = scale / fmaxf(sqrtf(s), 1e-12f);
    __hip_bfloat16 h = __float2bfloat16(v * inv);
    dst[row * HD + lane] = *reinterpret_cast<ushort*>(&h);
}

// ---- prep: normalized memories -> swizzled MFMA B-fragment order ----
__global__ __launch_bounds__(256) void prep_m_swz(const float* __restrict__ mem,
                                                  ushort* __restrict__ mbs) {
    const int wave = threadIdx.x >> 6, lane = threadIdx.x & 63;
    const int row = blockIdx.x * 4 + wave;   // n
    float v = mem[row * HD + lane];          // k = lane
    float s = v * v;
#pragma unroll
    for (int o = 32; o; o >>= 1) s += __shfl_xor(s, o, 64);
    const float inv = 1.0f / fmaxf(sqrtf(s), 1e-12f);
    __hip_bfloat16 h = __float2bfloat16(v * inv);
    const int t = row >> 4, c = row & 15;
    const int k = lane;
    const int f = k >> 5, q = (k >> 3) & 3, j = k & 7;
    mbs[(long)t * 1024 + f * 512 + (q * 16 + c) * 8 + j] =
        *reinterpret_cast<ushort*>(&h);
}

// A-frag: lane holds xb[m0+(lane&15)][q*8..+7], q=lane>>4.
// C/D: col = lane&15, row = q*4 + reg   [verified layout, learn_hip m89/m91].
__global__ __launch_bounds__(256, 8) void k_main(const ushort* __restrict__ xb,
                                                 const ushort* __restrict__ mbs,
                                                 float* __restrict__ stats,
                                                 uint* __restrict__ masks,
                                                 float* __restrict__ out_w,
                                                 float* __restrict__ out_read) {
    const int tid = threadIdx.x;
    const int wv = tid >> 6, lane = tid & 63;
    const int q = lane >> 4, c = lane & 15;
    const int m0 = blockIdx.x * 16;

    __shared__ float sS[4][16];   // 256 B total LDS

    const bf16x8 a0 = *(const bf16x8*)(xb + (long)(m0 + c) * HD + q * 8);
    const bf16x8 a1 = *(const bf16x8*)(xb + (long)(m0 + c) * HD + q * 8 + 32);
    const ushort* mstrip = mbs + (long)(wv * 64) * 1024;   // wave's 64 chunks
    float4* zbase = (float4*)(out_w + (long)m0 * NM);      // block's 256 KB
    const float4 z4 = make_float4(0.0f, 0.0f, 0.0f, 0.0f);

    // ---- P1: sum-exp + coarse gate bank + interleaved zero-stores ----
    float tmax8[8];
    float sm[4] = {0.0f, 0.0f, 0.0f, 0.0f};
    for (int g = 0; g < 8; g++) {
        float tm = -1e30f;
#pragma unroll 4
        for (int ii = 0; ii < 8; ii++) {
            const int i = g * 8 + ii;
            const ushort* mc = mstrip + (long)i * 1024 + lane * 8;
            const bf16x8 b0 = *(const bf16x8*)(mc);
            const bf16x8 b1 = *(const bf16x8*)(mc + 512);
            zbase[i * 256 + tid] = z4;   // fire-and-forget 1 KB/wave store
            f32x4 t = {0.0f, 0.0f, 0.0f, 0.0f};
            t = __builtin_amdgcn_mfma_f32_16x16x32_bf16(a0, b0, t, 0, 0, 0);
            t = __builtin_amdgcn_mfma_f32_16x16x32_bf16(a1, b1, t, 0, 0, 0);
            tm = fmaxf(tm, fmaxf(fmaxf(t[0], t[1]), fmaxf(t[2], t[3])));
#pragma unroll
            for (int r = 0; r < 4; r++) sm[r] += __expf(t[r]);
        }
        tmax8[g] = tm;
    }
#pragma unroll
    for (int o = 1; o < 16; o <<= 1)
#pragma unroll
        for (int r = 0; r < 4; r++) sm[r] += __shfl_xor(sm[r], o, 64);
    if (c == 0)
#pragma unroll
        for (int r = 0; r < 4; r++) sS[wv][q * 4 + r] = sm[r];
    // LDS-only barrier: do NOT drain the interleaved global stores
    __asm__ volatile("s_waitcnt lgkmcnt(0)\n\ts_barrier" ::: "memory");

    float Sr[4], tmin = 1e30f;
#pragma unroll
    for (int r = 0; r < 4; r++) {
        const float S = sS[0][q * 4 + r] + sS[1][q * 4 + r] +
                        sS[2][q * 4 + r] + sS[3][q * 4 + r];
        Sr[r] = S;
        tmin = fminf(tmin, __logf(0.0025f * S) - 1e-3f);  // conservative tau
    }
    uint dmask = 0;
#pragma unroll
    for (int g = 0; g < 8; g++)
        if (__ballot(tmax8[g] > tmin)) dmask |= 1u << g;
    if (lane == 0) masks[blockIdx.x * 4 + wv] = dmask;
    if (wv == 0 && c == 0)
#pragma unroll
        for (int r = 0; r < 4; r++) stats[m0 + q * 4 + r] = Sr[r];
    // zero out_read rows (4 KB/block, one float4 per thread)
    ((float4*)(out_read + (long)m0 * HD))[tid] = z4;
}

// ---- k_fix: no-op for clean blocks; exact recompute for dirty ones ----
__global__ __launch_bounds__(256) void k_fix(const ushort* __restrict__ xb,
                                             const ushort* __restrict__ mbs,
                                             const float* __restrict__ mem,
                                             const float* __restrict__ stats,
                                             const uint* __restrict__ masks,
                                             float* __restrict__ out_w,
                                             float* __restrict__ out_read) {
    const int tid = threadIdx.x;
    const int wv = tid >> 6, lane = tid & 63;
    const int q = lane >> 4, c = lane & 15;
    const int m0 = blockIdx.x * 16;

    __shared__ uint  sM[4];
    __shared__ float sL[4][16];

    if (lane == 0) sM[wv] = masks[blockIdx.x * 4 + wv];
    __syncthreads();
    if (!(sM[0] | sM[1] | sM[2] | sM[3])) return;  // clean (common): done

    // ============== dirty block (rare): exact path ==============
    const uint dmask = sM[wv];
    const bf16x8 a0 = *(const bf16x8*)(xb + (long)(m0 + c) * HD + q * 8);
    const bf16x8 a1 = *(const bf16x8*)(xb + (long)(m0 + c) * HD + q * 8 + 32);
    const ushort* mstrip = mbs + (long)(wv * 64) * 1024;
    float rS[4];
#pragma unroll
    for (int r = 0; r < 4; r++) rS[r] = 1.0f / stats[m0 + q * 4 + r];

    // gated L1 (only dirty groups can hold survivors)
    float l1[4] = {0.0f, 0.0f, 0.0f, 0.0f};
    for (int g = 0; g < 8; g++) {
        if (!((dmask >> g) & 1u)) continue;   // wave-uniform
        for (int ii = 0; ii < 8; ii++) {
            const int i = g * 8 + ii;
            const ushort* mc = mstrip + (long)i * 1024 + lane * 8;
            const bf16x8 b0 = *(const bf16x8*)(mc);
            const bf16x8 b1 = *(const bf16x8*)(mc + 512);
            f32x4 t = {0.0f, 0.0f, 0.0f, 0.0f};
            t = __builtin_amdgcn_mfma_f32_16x16x32_bf16(a0, b0, t, 0, 0, 0);
            t = __builtin_amdgcn_mfma_f32_16x16x32_bf16(a1, b1, t, 0, 0, 0);
#pragma unroll
            for (int r = 0; r < 4; r++) {
                float w = __expf(t[r]) * rS[r];
                float d = w - 0.0025f;
                l1[r] += __fdividef(fmaxf(d, 0.0f) * w, fabsf(d) + 1e-12f);
            }
        }
    }
#pragma unroll
    for (int o = 1; o < 16; o <<= 1)
#pragma unroll
        for (int r = 0; r < 4; r++) l1[r] += __shfl_xor(l1[r], o, 64);
    if (c == 0)
#pragma unroll
        for (int r = 0; r < 4; r++) sL[wv][q * 4 + r] = l1[r];
    __syncthreads();
    float rL[4];
#pragma unroll
    for (int r = 0; r < 4; r++)
        rL[r] = 1.0f / fmaxf(sL[0][q * 4 + r] + sL[1][q * 4 + r] +
                             sL[2][q * 4 + r] + sL[3][q * 4 + r], 1e-12f);

    // recompute dirty groups: exact weights overwrite the drained zeros;
    // ballot-sparse read accumulation -> atomicAdd (out_read pre-zeroed)
    float racc[16];
#pragma unroll
    for (int r = 0; r < 16; r++) racc[r] = 0.0f;
    bool anyr = false;
    float* wbase = out_w + (long)(m0 + q * 4) * NM + c;
    for (int g = 0; g < 8; g++) {
        if (!((dmask >> g) & 1u)) continue;
        for (int ii = 0; ii < 8; ii++) {
            const int i = g * 8 + ii;
            const int n0 = wv * 1024 + i * 16;
            const ushort* mc = mstrip + (long)i * 1024 + lane * 8;
            const bf16x8 b0 = *(const bf16x8*)(mc);
            const bf16x8 b1 = *(const bf16x8*)(mc + 512);
            f32x4 t = {0.0f, 0.0f, 0.0f, 0.0f};
            t = __builtin_amdgcn_mfma_f32_16x16x32_bf16(a0, b0, t, 0, 0, 0);
            t = __builtin_amdgcn_mfma_f32_16x16x32_bf16(a1, b1, t, 0, 0, 0);
            float wf[4];
#pragma unroll
            for (int r = 0; r < 4; r++) {
                float w  = __expf(t[r]) * rS[r];
                float d  = w - 0.0025f;
                float sh = __fdividef(fmaxf(d, 0.0f) * w, fabsf(d) + 1e-12f);
                wf[r] = sh * rL[r];
                wbase[(long)r * NM + n0] = wf[r];
            }
            const bool nz = (wf[0] != 0.0f) | (wf[1] != 0.0f) |
                            (wf[2] != 0.0f) | (wf[3] != 0.0f);
            unsigned long long mask = __ballot(nz);
            if (mask) anyr = true;
            while (mask) {
                const int j = __ffsll((long long)mask) - 1;
                mask &= (mask - 1);
                const int qj = j >> 4, cj = j & 15;
                float b0v = __shfl(wf[0], j, 64), b1v = __shfl(wf[1], j, 64);
                float b2v = __shfl(wf[2], j, 64), b3v = __shfl(wf[3], j, 64);
                const float mv = mem[(long)(n0 + cj) * HD + lane];
                switch (qj) {  // wave-uniform branch
                    case 0: racc[0]  += b0v * mv; racc[1]  += b1v * mv;
                            racc[2]  += b2v * mv; racc[3]  += b3v * mv; break;
                    case 1: racc[4]  += b0v * mv; racc[5]  += b1v * mv;
                            racc[6]  += b2v * mv; racc[7]  += b3v * mv; break;
                    case 2: racc[8]  += b0v * mv; racc[9]  += b1v * mv;
                            racc[10] += b2v * mv; racc[11] += b3v * mv; break;
                    default: racc[12] += b0v * mv; racc[13] += b1v * mv;
                             racc[14] += b2v * mv; racc[15] += b3v * mv; break;
                }
            }
        }
    }
    if (anyr) {
#pragma unroll
        for (int r = 0; r < 16; r++)
            atomicAdd(out_read + (long)(m0 + r) * HD + lane, racc[r]);
    }
}

extern "C" void kernel_launch(void* const* d_in, const int* in_sizes, int n_in,
                              void* d_out, int out_size, void* d_ws, size_t ws_size,
                              hipStream_t stream) {
    const float* x   = (const float*)d_in[0];
    const float* mem = (const float*)d_in[1];
    ushort* xb       = (ushort*)d_ws;                 // 4 MB
    ushort* mbs      = xb + (long)NROWS * HD;         // 512 KB (swizzled B)
    float*  stats    = (float*)(mbs + (long)NM * HD); // 128 KB per-row S
    uint*   masks    = (uint*)(stats + NROWS);        // 32 KB wave dirty masks
    float* out_read  = (float*)d_out;                 // [32768*64]
    float* out_w     = out_read + (long)NROWS * HD;   // [32768*4096]

    prep_rows<<<NROWS / 4, 256, 0, stream>>>(x, xb, 2.0f);  // 1/T folded
    prep_m_swz<<<NM / 4, 256, 0, stream>>>(mem, mbs);
    k_main<<<NROWS / 16, 256, 0, stream>>>(xb, mbs, stats, masks, out_w, out_read);
    k_fix<<<NROWS / 16, 256, 0, stream>>>(xb, mbs, mem, stats, masks, out_w, out_read);
}

// Round 16
// 541.353 us; speedup vs baseline: 1.0317x; 1.0154x over previous
//
#include <hip/hip_runtime.h>
#include <hip/hip_bf16.h>

// Round 15b: non-temporal store stream (compile fix: nt builtin needs clang
// ext_vector types, not HIP_vector_type float4 -> use f32x4).
// Diagnosis of the R8-R14 ~180 µs plateau: P1 costs ~170 µs = 64 iters x
// ~800 cyc -- HBM-miss latency on the b-fragment loads.  The 546 MB
// weight-store stream write-allocates through each XCD's 4 MB L2,
// evicting the 512 KB mbs table continuously.  Fix: ALL output stores use
// __builtin_nontemporal_store (nt: no L2 allocate) so mbs stays
// L2-resident for P1.
//   k_ps (hot, 512 thr, launch_bounds(512,8), LDS 256 B, no dirty code):
//     waves 4-7 stream the block's 256 KB zero weights + out_read zeros
//     (nt); waves 0-3 run P1 (sum-exp via MFMA, loads only), gate
//     tau = ln(lambda*S) - 1e-3, write masks + per-row S to ws.
//     One matched __syncthreads joins at max(T_P1, T_store).
//   k_fix (cold): clean block (common: max w ~6e-4 << lambda=2.5e-3)
//     returns after 1 load; dirty blocks recompute bit-identically
//     (same MFMA/exp bits, rS from stored S), gated L1, exact weights
//     overwrite the (kernel-boundary-committed) zeros, ballot-sparse
//     read -> atomicAdd into pre-zeroed out_read.

#define NM 4096
#define HD 64
#define NROWS 32768  // 16*2048

typedef short bf16x8 __attribute__((ext_vector_type(8)));
typedef float f32x4  __attribute__((ext_vector_type(4)));

// ---- prep: normalized x rows -> bf16 [row][k], scale folded in ----
__global__ __launch_bounds__(256) void prep_rows(const float* __restrict__ src,
                                                 ushort* __restrict__ dst,
                                                 float scale) {
    const int wave = threadIdx.x >> 6, lane = threadIdx.x & 63;
    const long row = (long)blockIdx.x * 4 + wave;
    float v = src[row * HD + lane];
    float s = v * v;
#pragma unroll
    for (int o = 32; o; o >>= 1) s += __shfl_xor(s, o, 64);
    const float inv = scale / fmaxf(sqrtf(s), 1e-12f);
    __hip_bfloat16 h = __float2bfloat16(v * inv);
    dst[row * HD + lane] = *reinterpret_cast<ushort*>(&h);
}

// ---- prep: normalized memories -> swizzled MFMA B-fragment order ----
__global__ __launch_bounds__(256) void prep_m_swz(const float* __restrict__ mem,
                                                  ushort* __restrict__ mbs) {
    const int wave = threadIdx.x >> 6, lane = threadIdx.x & 63;
    const int row = blockIdx.x * 4 + wave;   // n
    float v = mem[row * HD + lane];          // k = lane
    float s = v * v;
#pragma unroll
    for (int o = 32; o; o >>= 1) s += __shfl_xor(s, o, 64);
    const float inv = 1.0f / fmaxf(sqrtf(s), 1e-12f);
    __hip_bfloat16 h = __float2bfloat16(v * inv);
    const int t = row >> 4, c = row & 15;
    const int k = lane;
    const int f = k >> 5, q = (k >> 3) & 3, j = k & 7;
    mbs[(long)t * 1024 + f * 512 + (q * 16 + c) * 8 + j] =
        *reinterpret_cast<ushort*>(&h);
}

// A-frag: lane holds xb[m0+(lane&15)][q*8..+7], q=lane>>4.
// C/D: col = lane&15, row = q*4 + reg   [verified layout, learn_hip m89/m91].
__global__ __launch_bounds__(512, 8) void k_ps(const ushort* __restrict__ xb,
                                               const ushort* __restrict__ mbs,
                                               float* __restrict__ stats,
                                               uint* __restrict__ masks,
                                               float* __restrict__ out_w,
                                               float* __restrict__ out_read) {
    const int tid = threadIdx.x;
    const int wv = tid >> 6, lane = tid & 63;   // wv 0..7
    const int m0 = blockIdx.x * 16;

    __shared__ float sS[4][16];   // 256 B total LDS
    const f32x4 z4 = {0.0f, 0.0f, 0.0f, 0.0f};

    if (wv >= 4) {
        // ============ storer waves (4..7): nt zero streams ============
        const int sw = wv - 4;
        f32x4* base = (f32x4*)(out_w + (long)m0 * NM);   // 16384 f32x4
#pragma unroll 8
        for (int it = 0; it < 64; it++)
            __builtin_nontemporal_store(z4, base + it * 256 + sw * 64 + lane);
        if (sw == 0) {
            f32x4* rb = (f32x4*)(out_read + (long)m0 * HD);  // 256 f32x4
#pragma unroll
            for (int it = 0; it < 4; it++)
                __builtin_nontemporal_store(z4, rb + it * 64 + lane);
        }
        __syncthreads();   // B1 (matched): joins at max(T_store, T_P1)
        return;
    }

    // ================= compute waves (0..3): P1 only =================
    const int q = lane >> 4, c = lane & 15;
    const bf16x8 a0 = *(const bf16x8*)(xb + (long)(m0 + c) * HD + q * 8);
    const bf16x8 a1 = *(const bf16x8*)(xb + (long)(m0 + c) * HD + q * 8 + 32);
    const ushort* mstrip = mbs + (long)(wv * 64) * 1024;   // wave's 64 chunks

    float tmax8[8];
    float sm[4] = {0.0f, 0.0f, 0.0f, 0.0f};
    for (int g = 0; g < 8; g++) {
        float tm = -1e30f;
#pragma unroll 4
        for (int ii = 0; ii < 8; ii++) {
            const int i = g * 8 + ii;
            const ushort* mc = mstrip + (long)i * 1024 + lane * 8;
            const bf16x8 b0 = *(const bf16x8*)(mc);
            const bf16x8 b1 = *(const bf16x8*)(mc + 512);
            f32x4 t = {0.0f, 0.0f, 0.0f, 0.0f};
            t = __builtin_amdgcn_mfma_f32_16x16x32_bf16(a0, b0, t, 0, 0, 0);
            t = __builtin_amdgcn_mfma_f32_16x16x32_bf16(a1, b1, t, 0, 0, 0);
            tm = fmaxf(tm, fmaxf(fmaxf(t[0], t[1]), fmaxf(t[2], t[3])));
#pragma unroll
            for (int r = 0; r < 4; r++) sm[r] += __expf(t[r]);
        }
        tmax8[g] = tm;
    }
#pragma unroll
    for (int o = 1; o < 16; o <<= 1)
#pragma unroll
        for (int r = 0; r < 4; r++) sm[r] += __shfl_xor(sm[r], o, 64);
    if (c == 0)
#pragma unroll
        for (int r = 0; r < 4; r++) sS[wv][q * 4 + r] = sm[r];
    __syncthreads();   // B1 (matched with storers)

    float Sr[4], tmin = 1e30f;
#pragma unroll
    for (int r = 0; r < 4; r++) {
        const float S = sS[0][q * 4 + r] + sS[1][q * 4 + r] +
                        sS[2][q * 4 + r] + sS[3][q * 4 + r];
        Sr[r] = S;
        tmin = fminf(tmin, __logf(0.0025f * S) - 1e-3f);  // conservative tau
    }
    uint dmask = 0;
#pragma unroll
    for (int g = 0; g < 8; g++)
        if (__ballot(tmax8[g] > tmin)) dmask |= 1u << g;
    if (lane == 0) masks[blockIdx.x * 4 + wv] = dmask;
    if (wv == 0 && c == 0)
#pragma unroll
        for (int r = 0; r < 4; r++) stats[m0 + q * 4 + r] = Sr[r];
}

// ---- k_fix: no-op for clean blocks; exact recompute for dirty ones ----
__global__ __launch_bounds__(256) void k_fix(const ushort* __restrict__ xb,
                                             const ushort* __restrict__ mbs,
                                             const float* __restrict__ mem,
                                             const float* __restrict__ stats,
                                             const uint* __restrict__ masks,
                                             float* __restrict__ out_w,
                                             float* __restrict__ out_read) {
    const int tid = threadIdx.x;
    const int wv = tid >> 6, lane = tid & 63;
    const int q = lane >> 4, c = lane & 15;
    const int m0 = blockIdx.x * 16;

    __shared__ uint  sM[4];
    __shared__ float sL[4][16];

    if (lane == 0) sM[wv] = masks[blockIdx.x * 4 + wv];
    __syncthreads();
    if (!(sM[0] | sM[1] | sM[2] | sM[3])) return;  // clean (common): done

    // ============== dirty block (rare): exact path ==============
    const uint dmask = sM[wv];
    const bf16x8 a0 = *(const bf16x8*)(xb + (long)(m0 + c) * HD + q * 8);
    const bf16x8 a1 = *(const bf16x8*)(xb + (long)(m0 + c) * HD + q * 8 + 32);
    const ushort* mstrip = mbs + (long)(wv * 64) * 1024;
    float rS[4];
#pragma unroll
    for (int r = 0; r < 4; r++) rS[r] = 1.0f / stats[m0 + q * 4 + r];

    // gated L1 (only dirty groups can hold survivors)
    float l1[4] = {0.0f, 0.0f, 0.0f, 0.0f};
    for (int g = 0; g < 8; g++) {
        if (!((dmask >> g) & 1u)) continue;   // wave-uniform
        for (int ii = 0; ii < 8; ii++) {
            const int i = g * 8 + ii;
            const ushort* mc = mstrip + (long)i * 1024 + lane * 8;
            const bf16x8 b0 = *(const bf16x8*)(mc);
            const bf16x8 b1 = *(const bf16x8*)(mc + 512);
            f32x4 t = {0.0f, 0.0f, 0.0f, 0.0f};
            t = __builtin_amdgcn_mfma_f32_16x16x32_bf16(a0, b0, t, 0, 0, 0);
            t = __builtin_amdgcn_mfma_f32_16x16x32_bf16(a1, b1, t, 0, 0, 0);
#pragma unroll
            for (int r = 0; r < 4; r++) {
                float w = __expf(t[r]) * rS[r];
                float d = w - 0.0025f;
                l1[r] += __fdividef(fmaxf(d, 0.0f) * w, fabsf(d) + 1e-12f);
            }
        }
    }
#pragma unroll
    for (int o = 1; o < 16; o <<= 1)
#pragma unroll
        for (int r = 0; r < 4; r++) l1[r] += __shfl_xor(l1[r], o, 64);
    if (c == 0)
#pragma unroll
        for (int r = 0; r < 4; r++) sL[wv][q * 4 + r] = l1[r];
    __syncthreads();
    float rL[4];
#pragma unroll
    for (int r = 0; r < 4; r++)
        rL[r] = 1.0f / fmaxf(sL[0][q * 4 + r] + sL[1][q * 4 + r] +
                             sL[2][q * 4 + r] + sL[3][q * 4 + r], 1e-12f);

    // recompute dirty groups: exact weights overwrite committed zeros;
    // ballot-sparse read accumulation -> atomicAdd (out_read pre-zeroed)
    float racc[16];
#pragma unroll
    for (int r = 0; r < 16; r++) racc[r] = 0.0f;
    bool anyr = false;
    float* wbase = out_w + (long)(m0 + q * 4) * NM + c;
    for (int g = 0; g < 8; g++) {
        if (!((dmask >> g) & 1u)) continue;
        for (int ii = 0; ii < 8; ii++) {
            const int i = g * 8 + ii;
            const int n0 = wv * 1024 + i * 16;
            const ushort* mc = mstrip + (long)i * 1024 + lane * 8;
            const bf16x8 b0 = *(const bf16x8*)(mc);
            const bf16x8 b1 = *(const bf16x8*)(mc + 512);
            f32x4 t = {0.0f, 0.0f, 0.0f, 0.0f};
            t = __builtin_amdgcn_mfma_f32_16x16x32_bf16(a0, b0, t, 0, 0, 0);
            t = __builtin_amdgcn_mfma_f32_16x16x32_bf16(a1, b1, t, 0, 0, 0);
            float wf[4];
#pragma unroll
            for (int r = 0; r < 4; r++) {
                float w  = __expf(t[r]) * rS[r];
                float d  = w - 0.0025f;
                float sh = __fdividef(fmaxf(d, 0.0f) * w, fabsf(d) + 1e-12f);
                wf[r] = sh * rL[r];
                wbase[(long)r * NM + n0] = wf[r];
            }
            const bool nz = (wf[0] != 0.0f) | (wf[1] != 0.0f) |
                            (wf[2] != 0.0f) | (wf[3] != 0.0f);
            unsigned long long mask = __ballot(nz);
            if (mask) anyr = true;
            while (mask) {
                const int j = __ffsll((long long)mask) - 1;
                mask &= (mask - 1);
                const int qj = j >> 4, cj = j & 15;
                float b0v = __shfl(wf[0], j, 64), b1v = __shfl(wf[1], j, 64);
                float b2v = __shfl(wf[2], j, 64), b3v = __shfl(wf[3], j, 64);
                const float mv = mem[(long)(n0 + cj) * HD + lane];
                switch (qj) {  // wave-uniform branch
                    case 0: racc[0]  += b0v * mv; racc[1]  += b1v * mv;
                            racc[2]  += b2v * mv; racc[3]  += b3v * mv; break;
                    case 1: racc[4]  += b0v * mv; racc[5]  += b1v * mv;
                            racc[6]  += b2v * mv; racc[7]  += b3v * mv; break;
                    case 2: racc[8]  += b0v * mv; racc[9]  += b1v * mv;
                            racc[10] += b2v * mv; racc[11] += b3v * mv; break;
                    default: racc[12] += b0v * mv; racc[13] += b1v * mv;
                             racc[14] += b2v * mv; racc[15] += b3v * mv; break;
                }
            }
        }
    }
    if (anyr) {
#pragma unroll
        for (int r = 0; r < 16; r++)
            atomicAdd(out_read + (long)(m0 + r) * HD + lane, racc[r]);
    }
}

extern "C" void kernel_launch(void* const* d_in, const int* in_sizes, int n_in,
                              void* d_out, int out_size, void* d_ws, size_t ws_size,
                              hipStream_t stream) {
    const float* x   = (const float*)d_in[0];
    const float* mem = (const float*)d_in[1];
    ushort* xb       = (ushort*)d_ws;                 // 4 MB
    ushort* mbs      = xb + (long)NROWS * HD;         // 512 KB (swizzled B)
    float*  stats    = (float*)(mbs + (long)NM * HD); // 128 KB per-row S
    uint*   masks    = (uint*)(stats + NROWS);        // 32 KB wave dirty masks
    float* out_read  = (float*)d_out;                 // [32768*64]
    float* out_w     = out_read + (long)NROWS * HD;   // [32768*4096]

    prep_rows<<<NROWS / 4, 256, 0, stream>>>(x, xb, 2.0f);  // 1/T folded
    prep_m_swz<<<NM / 4, 256, 0, stream>>>(mem, mbs);
    k_ps<<<NROWS / 16, 512, 0, stream>>>(xb, mbs, stats, masks, out_w, out_read);
    k_fix<<<NROWS / 16, 256, 0, stream>>>(xb, mbs, mem, stats, masks, out_w, out_read);
}